// Round 6
// baseline (130.063 us; speedup 1.0000x reference)
//
#include <hip/hip_runtime.h>
#include <stdint.h>

#define CI 512
#define CO 512
#define HI 64
#define WI 64
#define HY 65
#define NB 8

typedef __bf16 bf16x8 __attribute__((ext_vector_type(8)));
typedef float f32x4 __attribute__((ext_vector_type(4)));

__device__ __forceinline__ unsigned short f2bf(float f) {
  unsigned int u = __float_as_uint(f);
  return (unsigned short)((u + 0x7fffu + ((u >> 16) & 1u)) >> 16);
}

// async global->LDS, 16B per lane. LDS dest = wave-uniform base + lane*16.
__device__ __forceinline__ void async16(void* lds, const void* g) {
  __builtin_amdgcn_global_load_lds(
      (const __attribute__((address_space(1))) uint32_t*)g,
      (__attribute__((address_space(3))) uint32_t*)lds, 16, 0, 0);
}

#define FENCE asm volatile("" ::: "memory")
#define BAR do { FENCE; __builtin_amdgcn_s_barrier(); FENCE; } while (0)

// ---------------- Kernel A: FIR prefilter (LDS-tiled separable) ----------------
#define CT 32
#define RT 13

__global__ __launch_bounds__(256) void fir_kernel(const float* __restrict__ x,
                                                  unsigned short* __restrict__ yt) {
  __shared__ float raw[CT][WI + 1];
  __shared__ float hrow[4][HY][CT];

  const int tid = threadIdx.x;
  const int bid = blockIdx.x;
  const int n = bid / 80;
  const int rem = bid % 80;
  const int c0 = (rem / 5) * CT;
  const int r0 = (rem % 5) * RT;

  const float* xb = x + ((size_t)n * CI + c0) * (HI * WI);

  const int lc = tid >> 3;
  const int lq = tid & 7;
  const int c = tid & (CT - 1);
  const int sb = tid >> 5;

  auto stage = [&](int hr) {
    __syncthreads();
    if ((unsigned)hr < (unsigned)HI) {
      const float* rowp = xb + ((size_t)lc * HI + hr) * WI;
      float4 a = *(const float4*)&rowp[lq * 4];
      float4 b = *(const float4*)&rowp[(lq + 8) * 4];
      raw[lc][lq * 4 + 0] = a.x; raw[lc][lq * 4 + 1] = a.y;
      raw[lc][lq * 4 + 2] = a.z; raw[lc][lq * 4 + 3] = a.w;
      raw[lc][(lq + 8) * 4 + 0] = b.x; raw[lc][(lq + 8) * 4 + 1] = b.y;
      raw[lc][(lq + 8) * 4 + 2] = b.z; raw[lc][(lq + 8) * 4 + 3] = b.w;
    }
    __syncthreads();
    const int slot = hr & 3;
    if ((unsigned)hr < (unsigned)HI) {
#pragma unroll
      for (int k = 0; k < 9; k++) {
        const int s = sb + (k << 3);
        if (s < HY) {
          float v = 0.f;
          if (s >= 2) v += raw[c][s - 2];
          if (s >= 1) v += 3.f * raw[c][s - 1];
          if (s <= 63) v += 3.f * raw[c][s];
          if (s <= 62) v += raw[c][s + 1];
          hrow[slot][s][c] = v;
        }
      }
    } else {
#pragma unroll
      for (int k = 0; k < 9; k++) {
        const int s = sb + (k << 3);
        if (s < HY) hrow[slot][s][c] = 0.f;
      }
    }
  };

  stage(r0 - 2);
  stage(r0 - 1);
  stage(r0);

  for (int i = 0; i < RT; i++) {
    const int r = r0 + i;
    stage(r + 1);
    __syncthreads();
    const int q0 = (r - 2) & 3, q1 = (r - 1) & 3, q2 = r & 3, q3 = (r + 1) & 3;
    unsigned short* yo = yt + (((size_t)n * HY + r) * HY) * CI + c0 + c;
#pragma unroll
    for (int k = 0; k < 9; k++) {
      const int s = sb + (k << 3);
      if (s < HY) {
        const float y = (hrow[q0][s][c] + 3.f * hrow[q1][s][c] +
                         3.f * hrow[q2][s][c] + hrow[q3][s][c]) * (1.f / 64.f);
        yo[(size_t)s * CI] = f2bf(y);
      }
    }
  }
}

// ---------------- Kernel B: weight transform ----------------
__global__ __launch_bounds__(256) void wt_kernel(const float* __restrict__ w,
                                                 unsigned short* __restrict__ wtb) {
  const int gid = blockIdx.x * 256 + threadIdx.x;
  const int ci = gid & (CI - 1);
  const int co = gid >> 9;
  const float* src = w + ((size_t)co * CI + ci) * 9;
#pragma unroll
  for (int t = 0; t < 9; t++) {
    wtb[((size_t)t * CO + co) * CI + ci] = f2bf(src[t]);
  }
}

// ---------------- Kernel B2: out = bias (pre-init for split-K atomics) ----------
__global__ __launch_bounds__(256) void init_kernel(const float* __restrict__ bias,
                                                   float* __restrict__ out) {
  const int gid = blockIdx.x * 256 + threadIdx.x;
  const float bv = bias[(gid >> 8) & 511];
  float4 v = {bv, bv, bv, bv};
  *(float4*)(out + (size_t)gid * 4) = v;
}

// ---------------- Kernel C: implicit-GEMM conv, 256x256 tile, 4-phase ----------
// A = Y [256 pos][64 ci], B = W [256 co][64 ci], BK=64, split-K=4 (18 steps).
// 8 waves (2 pos-groups x 4 co-groups), wave out 128 pos x 64 co, acc 8x4.
// Per K-step: 4 phases {ds_read frags -> barrier -> setprio 16 MFMA -> barrier};
// all 8 global_load_lds for tile t+1 issued at phase 1 (3-phase lead),
// vmcnt(0) gate at phase 4 (loads ~1500 cyc old -> near-free wait).
// XOR slot swizzle both sides; atomic-f32 epilogue onto bias-initialized out.
__global__ __launch_bounds__(512, 2) void conv_kernel(
    const unsigned short* __restrict__ wtb,
    const unsigned short* __restrict__ yt,
    float* __restrict__ out) {
  __shared__ unsigned short Ylds[2][256 * 64];   // 2 x 32 KB
  __shared__ unsigned short Wlds[2][256 * 64];   // 2 x 32 KB

  const int tid = threadIdx.x;
  // 8 blocks per XCD share one pos-tile (2 co x 4 split variants)
  const int pos_tile = blockIdx.x >> 3;          // 0..31
  const int variant = blockIdx.x & 7;
  const int co_t = (variant & 1) << 8;           // 0 / 256
  const int split = variant >> 1;                // 0..3
  const int ks0 = split * 18;
  const int m0 = pos_tile << 8;
  const int n = m0 >> 10;

  // ---- staging per-lane global offsets (swizzled source) ----
  uint32_t yoff[4], woff[4];
#pragma unroll
  for (int i = 0; i < 4; i++) {
    const int ch = tid + i * 512;                // chunk 0..2047
    const int p = ch >> 3, s = ch & 7;
    const int pos = m0 + p;
    const int ho = (pos & 1023) >> 5, wo = pos & 31;
    yoff[i] = (uint32_t)(((n * HY + 2 * ho) * HY + 2 * wo) * CI + ((s ^ (p & 7)) << 3));
    woff[i] = (uint32_t)((co_t + p) * CI + ((s ^ (p & 7)) << 3));
  }

  auto stg = [&](unsigned short* Yb, unsigned short* Wb, int gks) {
    const int tap = gks >> 3;
    const int ci0 = (gks & 7) << 6;
    const int kh = tap / 3, kw = tap - kh * 3;
    const unsigned short* ys = yt + (size_t)(kh * HY + kw) * CI + ci0;
    const unsigned short* ws = wtb + (size_t)tap * (CO * CI) + ci0;
#pragma unroll
    for (int i = 0; i < 4; i++)
      async16(Yb + (size_t)(tid + i * 512) * 8, ys + yoff[i]);
#pragma unroll
    for (int i = 0; i < 4; i++)
      async16(Wb + (size_t)(tid + i * 512) * 8, ws + woff[i]);
  };

  // ---- compute-side fragment offsets (swizzled read) ----
  const int wv = tid >> 6;
  const int mg = wv >> 2;            // pos half 0/1
  const int ng = wv & 3;             // co quarter
  const int l = tid & 63;
  const int ll = l & 15, kg = l >> 4;
  const int sw = ll & 7;

  int yidx[8][2], widx[4][2];
#pragma unroll
  for (int mi = 0; mi < 8; mi++)
#pragma unroll
    for (int kk = 0; kk < 2; kk++)
      yidx[mi][kk] = (mg * 128 + mi * 16 + ll) * 64 + ((((kk << 2) | kg) ^ sw) << 3);
#pragma unroll
  for (int nf = 0; nf < 4; nf++)
#pragma unroll
    for (int kk = 0; kk < 2; kk++)
      widx[nf][kk] = (ng * 64 + nf * 16 + ll) * 64 + ((((kk << 2) | kg) ^ sw) << 3);

  f32x4 acc[8][4] = {};

#define LDF(base, idx) (*(const bf16x8*)((base) + (idx)))
#define MF4(MI, YV, WA, WB, WC, WD)                                              \
  acc[MI][0] = __builtin_amdgcn_mfma_f32_16x16x32_bf16(WA, YV, acc[MI][0], 0, 0, 0); \
  acc[MI][1] = __builtin_amdgcn_mfma_f32_16x16x32_bf16(WB, YV, acc[MI][1], 0, 0, 0); \
  acc[MI][2] = __builtin_amdgcn_mfma_f32_16x16x32_bf16(WC, YV, acc[MI][2], 0, 0, 0); \
  acc[MI][3] = __builtin_amdgcn_mfma_f32_16x16x32_bf16(WD, YV, acc[MI][3], 0, 0, 0);

#define KSTEP(CUR, DO_STAGE, GKS)                                         \
  {                                                                       \
    const unsigned short* Yc = &Ylds[CUR][0];                             \
    const unsigned short* Wc = &Wlds[CUR][0];                             \
    /* phase 1: W kk0 + Y mi0-3 kk0; stage next tile (8 gloads) */        \
    bf16x8 w0 = LDF(Wc, widx[0][0]), w1 = LDF(Wc, widx[1][0]);            \
    bf16x8 w2 = LDF(Wc, widx[2][0]), w3 = LDF(Wc, widx[3][0]);            \
    bf16x8 y0 = LDF(Yc, yidx[0][0]), y1 = LDF(Yc, yidx[1][0]);            \
    bf16x8 y2 = LDF(Yc, yidx[2][0]), y3 = LDF(Yc, yidx[3][0]);            \
    bf16x8 v0, v1, v2, v3;                                                \
    if (DO_STAGE) stg(&Ylds[(CUR) ^ 1][0], &Wlds[(CUR) ^ 1][0], (GKS));   \
    BAR;                                                                  \
    __builtin_amdgcn_s_setprio(1);                                        \
    MF4(0, y0, w0, w1, w2, w3); MF4(1, y1, w0, w1, w2, w3);               \
    MF4(2, y2, w0, w1, w2, w3); MF4(3, y3, w0, w1, w2, w3);               \
    __builtin_amdgcn_s_setprio(0);                                        \
    BAR;                                                                  \
    /* phase 2: Y mi4-7 kk0 + W kk1 */                                    \
    y0 = LDF(Yc, yidx[4][0]); y1 = LDF(Yc, yidx[5][0]);                   \
    y2 = LDF(Yc, yidx[6][0]); y3 = LDF(Yc, yidx[7][0]);                   \
    v0 = LDF(Wc, widx[0][1]); v1 = LDF(Wc, widx[1][1]);                   \
    v2 = LDF(Wc, widx[2][1]); v3 = LDF(Wc, widx[3][1]);                   \
    BAR;                                                                  \
    __builtin_amdgcn_s_setprio(1);                                        \
    MF4(4, y0, w0, w1, w2, w3); MF4(5, y1, w0, w1, w2, w3);               \
    MF4(6, y2, w0, w1, w2, w3); MF4(7, y3, w0, w1, w2, w3);               \
    __builtin_amdgcn_s_setprio(0);                                        \
    BAR;                                                                  \
    /* phase 3: Y mi0-3 kk1 */                                            \
    y0 = LDF(Yc, yidx[0][1]); y1 = LDF(Yc, yidx[1][1]);                   \
    y2 = LDF(Yc, yidx[2][1]); y3 = LDF(Yc, yidx[3][1]);                   \
    BAR;                                                                  \
    __builtin_amdgcn_s_setprio(1);                                        \
    MF4(0, y0, v0, v1, v2, v3); MF4(1, y1, v0, v1, v2, v3);               \
    MF4(2, y2, v0, v1, v2, v3); MF4(3, y3, v0, v1, v2, v3);               \
    __builtin_amdgcn_s_setprio(0);                                        \
    BAR;                                                                  \
    /* phase 4: Y mi4-7 kk1; vmcnt gate for next tile */                  \
    y0 = LDF(Yc, yidx[4][1]); y1 = LDF(Yc, yidx[5][1]);                   \
    y2 = LDF(Yc, yidx[6][1]); y3 = LDF(Yc, yidx[7][1]);                   \
    if (DO_STAGE) { asm volatile("s_waitcnt vmcnt(0)" ::: "memory"); }    \
    BAR;                                                                  \
    __builtin_amdgcn_s_setprio(1);                                        \
    MF4(4, y0, v0, v1, v2, v3); MF4(5, y1, v0, v1, v2, v3);               \
    MF4(6, y2, v0, v1, v2, v3); MF4(7, y3, v0, v1, v2, v3);               \
    __builtin_amdgcn_s_setprio(0);                                        \
    BAR;                                                                  \
  }

  // prologue: tile 0 into buf0, full drain
  stg(&Ylds[0][0], &Wlds[0][0], ks0);
  asm volatile("s_waitcnt vmcnt(0)" ::: "memory");
  BAR;

#pragma unroll 1
  for (int u = 0; u < 9; u++) {
    KSTEP(0, true, ks0 + 2 * u + 1);
    KSTEP(1, (u < 8), ks0 + 2 * u + 2);
  }
#undef KSTEP
#undef MF4
#undef LDF

  // Epilogue: C/D row=(lane>>4)*4+reg -> co; col=lane&15 -> pos (verified layout)
#pragma unroll
  for (int mi = 0; mi < 8; mi++) {
#pragma unroll
    for (int nf = 0; nf < 4; nf++) {
#pragma unroll
      for (int r = 0; r < 4; r++) {
        const int co = co_t + ng * 64 + nf * 16 + kg * 4 + r;
        const int pos = m0 + mg * 128 + mi * 16 + ll;
        atomicAdd(out + ((size_t)n * CO + co) * 1024 + (pos & 1023), acc[mi][nf][r]);
      }
    }
  }
}

extern "C" void kernel_launch(void* const* d_in, const int* in_sizes, int n_in,
                              void* d_out, int out_size, void* d_ws, size_t ws_size,
                              hipStream_t stream) {
  const float* x = (const float*)d_in[0];     // [8,512,64,64]
  const float* w = (const float*)d_in[1];     // [512,512,3,3]
  const float* bias = (const float*)d_in[2];  // [512]
  float* out = (float*)d_out;                 // [8,512,32,32]

  unsigned short* yt = (unsigned short*)d_ws;                    // 8*65*65*512 bf16
  unsigned short* wtb = yt + (size_t)NB * HY * HY * CI;          // 9*512*512 bf16

  fir_kernel<<<NB * (CI / CT) * 5, 256, 0, stream>>>(x, yt);     // 640 blocks
  wt_kernel<<<(CO * CI) / 256, 256, 0, stream>>>(w, wtb);        // 1024 blocks
  init_kernel<<<4096, 256, 0, stream>>>(bias, out);              // out = bias
  conv_kernel<<<256, 512, 0, stream>>>(wtb, yt, out);            // 256 blocks, splitK=4
}

// Round 7
// 125.599 us; speedup vs baseline: 1.0355x; 1.0355x over previous
//
#include <hip/hip_runtime.h>
#include <stdint.h>

#define CI 512
#define CO 512
#define HI 64
#define WI 64
#define HY 65
#define NB 8

typedef __bf16 bf16x8 __attribute__((ext_vector_type(8)));
typedef float f32x4 __attribute__((ext_vector_type(4)));

__device__ __forceinline__ unsigned short f2bf(float f) {
  unsigned int u = __float_as_uint(f);
  return (unsigned short)((u + 0x7fffu + ((u >> 16) & 1u)) >> 16);
}

// async global->LDS, 16B per lane. LDS dest = wave-uniform base + lane*16.
__device__ __forceinline__ void async16(void* lds, const void* g) {
  __builtin_amdgcn_global_load_lds(
      (const __attribute__((address_space(1))) uint32_t*)g,
      (__attribute__((address_space(3))) uint32_t*)lds, 16, 0, 0);
}

#define FENCE asm volatile("" ::: "memory")
#define BAR do { FENCE; __builtin_amdgcn_s_barrier(); FENCE; } while (0)

// ---------------- Kernel A: FIR prefilter (LDS-tiled separable) ----------------
#define CT 32
#define RT 13

__global__ __launch_bounds__(256) void fir_kernel(const float* __restrict__ x,
                                                  unsigned short* __restrict__ yt) {
  __shared__ float raw[CT][WI + 1];
  __shared__ float hrow[4][HY][CT];

  const int tid = threadIdx.x;
  const int bid = blockIdx.x;
  const int n = bid / 80;
  const int rem = bid % 80;
  const int c0 = (rem / 5) * CT;
  const int r0 = (rem % 5) * RT;

  const float* xb = x + ((size_t)n * CI + c0) * (HI * WI);

  const int lc = tid >> 3;
  const int lq = tid & 7;
  const int c = tid & (CT - 1);
  const int sb = tid >> 5;

  auto stage = [&](int hr) {
    __syncthreads();
    if ((unsigned)hr < (unsigned)HI) {
      const float* rowp = xb + ((size_t)lc * HI + hr) * WI;
      float4 a = *(const float4*)&rowp[lq * 4];
      float4 b = *(const float4*)&rowp[(lq + 8) * 4];
      raw[lc][lq * 4 + 0] = a.x; raw[lc][lq * 4 + 1] = a.y;
      raw[lc][lq * 4 + 2] = a.z; raw[lc][lq * 4 + 3] = a.w;
      raw[lc][(lq + 8) * 4 + 0] = b.x; raw[lc][(lq + 8) * 4 + 1] = b.y;
      raw[lc][(lq + 8) * 4 + 2] = b.z; raw[lc][(lq + 8) * 4 + 3] = b.w;
    }
    __syncthreads();
    const int slot = hr & 3;
    if ((unsigned)hr < (unsigned)HI) {
#pragma unroll
      for (int k = 0; k < 9; k++) {
        const int s = sb + (k << 3);
        if (s < HY) {
          float v = 0.f;
          if (s >= 2) v += raw[c][s - 2];
          if (s >= 1) v += 3.f * raw[c][s - 1];
          if (s <= 63) v += 3.f * raw[c][s];
          if (s <= 62) v += raw[c][s + 1];
          hrow[slot][s][c] = v;
        }
      }
    } else {
#pragma unroll
      for (int k = 0; k < 9; k++) {
        const int s = sb + (k << 3);
        if (s < HY) hrow[slot][s][c] = 0.f;
      }
    }
  };

  stage(r0 - 2);
  stage(r0 - 1);
  stage(r0);

  for (int i = 0; i < RT; i++) {
    const int r = r0 + i;
    stage(r + 1);
    __syncthreads();
    const int q0 = (r - 2) & 3, q1 = (r - 1) & 3, q2 = r & 3, q3 = (r + 1) & 3;
    unsigned short* yo = yt + (((size_t)n * HY + r) * HY) * CI + c0 + c;
#pragma unroll
    for (int k = 0; k < 9; k++) {
      const int s = sb + (k << 3);
      if (s < HY) {
        const float y = (hrow[q0][s][c] + 3.f * hrow[q1][s][c] +
                         3.f * hrow[q2][s][c] + hrow[q3][s][c]) * (1.f / 64.f);
        yo[(size_t)s * CI] = f2bf(y);
      }
    }
  }
}

// ---------------- Kernel B: weight transform ----------------
__global__ __launch_bounds__(256) void wt_kernel(const float* __restrict__ w,
                                                 unsigned short* __restrict__ wtb) {
  const int gid = blockIdx.x * 256 + threadIdx.x;
  const int ci = gid & (CI - 1);
  const int co = gid >> 9;
  const float* src = w + ((size_t)co * CI + ci) * 9;
#pragma unroll
  for (int t = 0; t < 9; t++) {
    wtb[((size_t)t * CO + co) * CI + ci] = f2bf(src[t]);
  }
}

// ---------------- Kernel B2: out = bias (pre-init for split-K atomics) ----------
__global__ __launch_bounds__(256) void init_kernel(const float* __restrict__ bias,
                                                   float* __restrict__ out) {
  const int gid = blockIdx.x * 256 + threadIdx.x;
  const float bv = bias[(gid >> 8) & 511];
  float4 v = {bv, bv, bv, bv};
  *(float4*)(out + (size_t)gid * 4) = v;
}

// ---------------- Kernel C: implicit-GEMM conv, 256x256 tile, fat 2-phase -------
// A = W [256 co][64 ci], B = Y [256 pos][64 ci], BK=64, split-K=4 (18 steps).
// 8 waves = 2 pos-halves x 4 co-quarters; wave out 128 pos x 64 co (acc 8x4).
// Per K-step (T3 2-phase, fat): issue 8 global_load_lds for t+1; vmcnt(8)
// gates own stage-t (t+1's 8 stay in flight across the whole ~2500-cyc
// compute -> latency fully hidden); barrier; 24 ds_read + 64 MFMA monolithic
// (compiler lgkmcnt scheduling); barrier. XOR slot swizzle both sides.
// XCD grouping (round-5-correct): blockIdx&7 = XCD; each XCD gets 4 pos-tiles
// x 8 variants (2 co x 4 split) -> Y-tile shared 8-way within one L2.
__global__ __launch_bounds__(512, 2) void conv_kernel(
    const unsigned short* __restrict__ wtb,
    const unsigned short* __restrict__ yt,
    float* __restrict__ out) {
  __shared__ unsigned short Ylds[2][256 * 64];   // 2 x 32 KB
  __shared__ unsigned short Wlds[2][256 * 64];   // 2 x 32 KB

  const int tid = threadIdx.x;
  const int xcd = blockIdx.x & 7;
  const int j = blockIdx.x >> 3;                 // 0..31 within XCD
  const int pos_tile = xcd * 4 + (j >> 3);       // 4 pos-tiles per XCD
  const int variant = j & 7;
  const int co_t = (variant & 1) << 8;           // 0 / 256
  const int split = variant >> 1;                // 0..3
  const int ks0 = split * 18;
  const int m0 = pos_tile << 8;
  const int n = m0 >> 10;

  // ---- staging per-lane global offsets (swizzled source) ----
  uint32_t yoff[4], woff[4];
#pragma unroll
  for (int i = 0; i < 4; i++) {
    const int ch = tid + i * 512;                // chunk 0..2047
    const int p = ch >> 3, s = ch & 7;
    const int pos = m0 + p;
    const int ho = (pos & 1023) >> 5, wo = pos & 31;
    yoff[i] = (uint32_t)(((n * HY + 2 * ho) * HY + 2 * wo) * CI + ((s ^ (p & 7)) << 3));
    woff[i] = (uint32_t)((co_t + p) * CI + ((s ^ (p & 7)) << 3));
  }

  auto stg = [&](unsigned short* Yb, unsigned short* Wb, int gks) {
    const int tap = gks >> 3;
    const int ci0 = (gks & 7) << 6;
    const int kh = tap / 3, kw = tap - kh * 3;
    const unsigned short* ys = yt + (size_t)(kh * HY + kw) * CI + ci0;
    const unsigned short* ws = wtb + (size_t)tap * (CO * CI) + ci0;
#pragma unroll
    for (int i = 0; i < 4; i++)
      async16(Yb + (size_t)(tid + i * 512) * 8, ys + yoff[i]);
#pragma unroll
    for (int i = 0; i < 4; i++)
      async16(Wb + (size_t)(tid + i * 512) * 8, ws + woff[i]);
  };

  // ---- compute-side fragment offsets (swizzled read) ----
  const int wv = tid >> 6;
  const int mg = wv >> 2;            // pos half 0/1
  const int ng = wv & 3;             // co quarter 0..3
  const int l = tid & 63;
  const int ll = l & 15, kg = l >> 4;
  const int sw = ll & 7;

  int yidx[8][2], widx[4][2];
#pragma unroll
  for (int mi = 0; mi < 8; mi++)
#pragma unroll
    for (int kk = 0; kk < 2; kk++)
      yidx[mi][kk] = (mg * 128 + mi * 16 + ll) * 64 + ((((kk << 2) | kg) ^ sw) << 3);
#pragma unroll
  for (int nf = 0; nf < 4; nf++)
#pragma unroll
    for (int kk = 0; kk < 2; kk++)
      widx[nf][kk] = (ng * 64 + nf * 16 + ll) * 64 + ((((kk << 2) | kg) ^ sw) << 3);

  f32x4 acc[8][4] = {};

  stg(&Ylds[0][0], &Wlds[0][0], ks0);

  for (int t = 0; t < 18; t++) {
    const int cur = t & 1;
    if (t < 17) stg(&Ylds[cur ^ 1][0], &Wlds[cur ^ 1][0], ks0 + t + 1);
    // gate: own stage-t landed (next stage's 8 loads remain in flight)
    if (t < 17) asm volatile("s_waitcnt vmcnt(8)" ::: "memory");
    else        asm volatile("s_waitcnt vmcnt(0)" ::: "memory");
    BAR;
    const unsigned short* Yc = &Ylds[cur][0];
    const unsigned short* Wc = &Wlds[cur][0];
#pragma unroll
    for (int kk = 0; kk < 2; kk++) {
      const bf16x8 w0 = *(const bf16x8*)(Wc + widx[0][kk]);
      const bf16x8 w1 = *(const bf16x8*)(Wc + widx[1][kk]);
      const bf16x8 w2 = *(const bf16x8*)(Wc + widx[2][kk]);
      const bf16x8 w3 = *(const bf16x8*)(Wc + widx[3][kk]);
      bf16x8 yv[8];
#pragma unroll
      for (int mi = 0; mi < 8; mi++) yv[mi] = *(const bf16x8*)(Yc + yidx[mi][kk]);
      __builtin_amdgcn_s_setprio(1);
#pragma unroll
      for (int mi = 0; mi < 8; mi++) {
        acc[mi][0] = __builtin_amdgcn_mfma_f32_16x16x32_bf16(w0, yv[mi], acc[mi][0], 0, 0, 0);
        acc[mi][1] = __builtin_amdgcn_mfma_f32_16x16x32_bf16(w1, yv[mi], acc[mi][1], 0, 0, 0);
        acc[mi][2] = __builtin_amdgcn_mfma_f32_16x16x32_bf16(w2, yv[mi], acc[mi][2], 0, 0, 0);
        acc[mi][3] = __builtin_amdgcn_mfma_f32_16x16x32_bf16(w3, yv[mi], acc[mi][3], 0, 0, 0);
      }
      __builtin_amdgcn_s_setprio(0);
    }
    BAR;  // protect buf[cur] before iter t+1 overwrites it
  }

  // Epilogue: C/D row=(lane>>4)*4+reg -> co; col=lane&15 -> pos (verified layout)
#pragma unroll
  for (int mi = 0; mi < 8; mi++) {
#pragma unroll
    for (int nf = 0; nf < 4; nf++) {
#pragma unroll
      for (int r = 0; r < 4; r++) {
        const int co = co_t + ng * 64 + nf * 16 + kg * 4 + r;
        const int pos = m0 + mg * 128 + mi * 16 + ll;
        atomicAdd(out + ((size_t)n * CO + co) * 1024 + (pos & 1023), acc[mi][nf][r]);
      }
    }
  }
}

extern "C" void kernel_launch(void* const* d_in, const int* in_sizes, int n_in,
                              void* d_out, int out_size, void* d_ws, size_t ws_size,
                              hipStream_t stream) {
  const float* x = (const float*)d_in[0];     // [8,512,64,64]
  const float* w = (const float*)d_in[1];     // [512,512,3,3]
  const float* bias = (const float*)d_in[2];  // [512]
  float* out = (float*)d_out;                 // [8,512,32,32]

  unsigned short* yt = (unsigned short*)d_ws;                    // 8*65*65*512 bf16
  unsigned short* wtb = yt + (size_t)NB * HY * HY * CI;          // 9*512*512 bf16

  fir_kernel<<<NB * (CI / CT) * 5, 256, 0, stream>>>(x, yt);     // 640 blocks
  wt_kernel<<<(CO * CI) / 256, 256, 0, stream>>>(w, wtb);        // 1024 blocks
  init_kernel<<<4096, 256, 0, stream>>>(bias, out);              // out = bias
  conv_kernel<<<256, 512, 0, stream>>>(wtb, yt, out);            // 256 blocks, splitK=4
}

// Round 8
// 119.493 us; speedup vs baseline: 1.0885x; 1.0511x over previous
//
#include <hip/hip_runtime.h>
#include <stdint.h>

#define CI 512
#define CO 512
#define HI 64
#define WI 64
#define HY 65
#define NB 8

typedef __bf16 bf16x8 __attribute__((ext_vector_type(8)));
typedef float f32x4 __attribute__((ext_vector_type(4)));

__device__ __forceinline__ unsigned short f2bf(float f) {
  unsigned int u = __float_as_uint(f);
  return (unsigned short)((u + 0x7fffu + ((u >> 16) & 1u)) >> 16);
}

// async global->LDS, 16B per lane. LDS dest = wave-uniform base + lane*16.
__device__ __forceinline__ void async16(void* lds, const void* g) {
  __builtin_amdgcn_global_load_lds(
      (const __attribute__((address_space(1))) uint32_t*)g,
      (__attribute__((address_space(3))) uint32_t*)lds, 16, 0, 0);
}

// ---------------- Kernel A: FIR prefilter (LDS-tiled separable) ----------------
#define CT 32
#define RT 13

__global__ __launch_bounds__(256) void fir_kernel(const float* __restrict__ x,
                                                  unsigned short* __restrict__ yt) {
  __shared__ float raw[CT][WI + 1];
  __shared__ float hrow[4][HY][CT];

  const int tid = threadIdx.x;
  const int bid = blockIdx.x;
  const int n = bid / 80;
  const int rem = bid % 80;
  const int c0 = (rem / 5) * CT;
  const int r0 = (rem % 5) * RT;

  const float* xb = x + ((size_t)n * CI + c0) * (HI * WI);

  const int lc = tid >> 3;
  const int lq = tid & 7;
  const int c = tid & (CT - 1);
  const int sb = tid >> 5;

  auto stage = [&](int hr) {
    __syncthreads();
    if ((unsigned)hr < (unsigned)HI) {
      const float* rowp = xb + ((size_t)lc * HI + hr) * WI;
      float4 a = *(const float4*)&rowp[lq * 4];
      float4 b = *(const float4*)&rowp[(lq + 8) * 4];
      raw[lc][lq * 4 + 0] = a.x; raw[lc][lq * 4 + 1] = a.y;
      raw[lc][lq * 4 + 2] = a.z; raw[lc][lq * 4 + 3] = a.w;
      raw[lc][(lq + 8) * 4 + 0] = b.x; raw[lc][(lq + 8) * 4 + 1] = b.y;
      raw[lc][(lq + 8) * 4 + 2] = b.z; raw[lc][(lq + 8) * 4 + 3] = b.w;
    }
    __syncthreads();
    const int slot = hr & 3;
    if ((unsigned)hr < (unsigned)HI) {
#pragma unroll
      for (int k = 0; k < 9; k++) {
        const int s = sb + (k << 3);
        if (s < HY) {
          float v = 0.f;
          if (s >= 2) v += raw[c][s - 2];
          if (s >= 1) v += 3.f * raw[c][s - 1];
          if (s <= 63) v += 3.f * raw[c][s];
          if (s <= 62) v += raw[c][s + 1];
          hrow[slot][s][c] = v;
        }
      }
    } else {
#pragma unroll
      for (int k = 0; k < 9; k++) {
        const int s = sb + (k << 3);
        if (s < HY) hrow[slot][s][c] = 0.f;
      }
    }
  };

  stage(r0 - 2);
  stage(r0 - 1);
  stage(r0);

  for (int i = 0; i < RT; i++) {
    const int r = r0 + i;
    stage(r + 1);
    __syncthreads();
    const int q0 = (r - 2) & 3, q1 = (r - 1) & 3, q2 = r & 3, q3 = (r + 1) & 3;
    unsigned short* yo = yt + (((size_t)n * HY + r) * HY) * CI + c0 + c;
#pragma unroll
    for (int k = 0; k < 9; k++) {
      const int s = sb + (k << 3);
      if (s < HY) {
        const float y = (hrow[q0][s][c] + 3.f * hrow[q1][s][c] +
                         3.f * hrow[q2][s][c] + hrow[q3][s][c]) * (1.f / 64.f);
        yo[(size_t)s * CI] = f2bf(y);
      }
    }
  }
}

// ---------------- Kernel B: weight transform ----------------
__global__ __launch_bounds__(256) void wt_kernel(const float* __restrict__ w,
                                                 unsigned short* __restrict__ wtb) {
  const int gid = blockIdx.x * 256 + threadIdx.x;
  const int ci = gid & (CI - 1);
  const int co = gid >> 9;
  const float* src = w + ((size_t)co * CI + ci) * 9;
#pragma unroll
  for (int t = 0; t < 9; t++) {
    wtb[((size_t)t * CO + co) * CI + ci] = f2bf(src[t]);
  }
}

// ---------------- Kernel B2: out = bias (pre-init for split-K atomics) ----------
__global__ __launch_bounds__(256) void init_kernel(const float* __restrict__ bias,
                                                   float* __restrict__ out) {
  const int gid = blockIdx.x * 256 + threadIdx.x;
  const float bv = bias[(gid >> 8) & 511];
  float4 v = {bv, bv, bv, bv};
  *(float4*)(out + (size_t)gid * 4) = v;
}

// ---------------- Kernel C: implicit-GEMM conv ----------------
// Round-3 structure (best measured: 65.6us) + split-K=2 for 3 blocks/CU.
// Tile: 64 co x 128 pos, BK=64, 36 k-steps per split (72 = 9 taps x 8 ci-blk).
// 256 threads = 4 waves (2 co x 2 pos), wave tile 32co x 64pos, acc 2x4.
// Double-buffered LDS (48 KB -> 3 co-resident blocks/CU; grid 1024 = 4/CU
// dispatched), global_load_lds staging issued before compute, drain barrier.
// XOR slot swizzle both sides. Atomic-f32 epilogue onto bias-initialized out.
__global__ __launch_bounds__(256, 3) void conv_kernel(
    const unsigned short* __restrict__ wtb,
    const unsigned short* __restrict__ yt,
    float* __restrict__ out) {
  __shared__ unsigned short Alds[2][64 * 64];    // 16 KB
  __shared__ unsigned short Blds[2][128 * 64];   // 32 KB

  const int tid = threadIdx.x;
  // XCD grouping: bid&7 = XCD; 16 variants (8 co x 2 split) share a pos-tile.
  const int xcd = blockIdx.x & 7;
  const int j = blockIdx.x >> 3;                 // 0..127
  const int pos_tile = xcd * 8 + (j >> 4);       // 0..63, 8 pos-tiles per XCD
  const int variant = j & 15;
  const int co_t = (variant >> 1) << 6;          // 0..448, 8 co-tiles of 64
  const int split = variant & 1;
  const int ks0 = split * 36;
  const int m0 = pos_tile << 7;                  // 128 pos per tile
  const int n = m0 >> 10;
  const int w = tid >> 6, l = tid & 63;

  // ---- staging lane-invariant global offsets (swizzled source) ----
  size_t aoff[2];
#pragma unroll
  for (int i = 0; i < 2; i++) {
    const int cch = i * 256 + w * 64 + l;        // A chunk id 0..511
    const int row = cch >> 3, s = cch & 7;
    aoff[i] = (size_t)(co_t + row) * CI + ((s ^ (row & 7)) << 3);
  }
  size_t boff[4];
#pragma unroll
  for (int i = 0; i < 4; i++) {
    const int cch = i * 256 + w * 64 + l;        // B chunk id 0..1023
    const int p = cch >> 3, s = cch & 7;
    const int pos = m0 + p;
    const int ho = (pos & 1023) >> 5, wo = pos & 31;
    boff[i] = (((size_t)n * HY + 2 * ho) * HY + 2 * wo) * CI + ((s ^ (p & 7)) << 3);
  }

  auto stage = [&](int b, int ks) {
    const int tap = ks >> 3;
    const int ci0 = (ks & 7) << 6;
    const int kh = tap / 3, kw = tap - kh * 3;
    const size_t ka = (size_t)tap * (CO * CI) + ci0;
    const size_t kb = (size_t)(kh * HY + kw) * CI + ci0;
    unsigned short* Ab = &Alds[b][0];
    unsigned short* Bb = &Blds[b][0];
#pragma unroll
    for (int i = 0; i < 2; i++)
      async16(Ab + (size_t)(i * 256 + w * 64 + l) * 8, wtb + ka + aoff[i]);
#pragma unroll
    for (int i = 0; i < 4; i++)
      async16(Bb + (size_t)(i * 256 + w * 64 + l) * 8, yt + kb + boff[i]);
  };

  // ---- compute-side fragment addresses (swizzled read) ----
  const int wco = (w >> 1) << 5;   // 0 / 32
  const int wpos = (w & 1) << 6;   // 0 / 64
  const int ll = l & 15, kg = l >> 4;
  const int a7 = ll & 7;

  int aidx[2][2], bidx[4][2];
#pragma unroll
  for (int m = 0; m < 2; m++)
#pragma unroll
    for (int kk = 0; kk < 2; kk++)
      aidx[m][kk] = (wco + m * 16 + ll) * 64 + ((((kk << 2) | kg) ^ a7) << 3);
#pragma unroll
  for (int nf = 0; nf < 4; nf++)
#pragma unroll
    for (int kk = 0; kk < 2; kk++)
      bidx[nf][kk] = (wpos + nf * 16 + ll) * 64 + ((((kk << 2) | kg) ^ a7) << 3);

  f32x4 acc[2][4] = {};

  stage(0, ks0);
  __syncthreads();

  int cur = 0;
  for (int t = 0; t < 36; t++) {
    if (t < 35) stage(cur ^ 1, ks0 + t + 1);   // loads in flight across compute
    const unsigned short* Ac = &Alds[cur][0];
    const unsigned short* Bc = &Blds[cur][0];
#pragma unroll
    for (int kk = 0; kk < 2; kk++) {
      const bf16x8 a0 = *(const bf16x8*)(Ac + aidx[0][kk]);
      const bf16x8 a1 = *(const bf16x8*)(Ac + aidx[1][kk]);
      const bf16x8 b0 = *(const bf16x8*)(Bc + bidx[0][kk]);
      const bf16x8 b1 = *(const bf16x8*)(Bc + bidx[1][kk]);
      const bf16x8 b2 = *(const bf16x8*)(Bc + bidx[2][kk]);
      const bf16x8 b3 = *(const bf16x8*)(Bc + bidx[3][kk]);
      acc[0][0] = __builtin_amdgcn_mfma_f32_16x16x32_bf16(a0, b0, acc[0][0], 0, 0, 0);
      acc[0][1] = __builtin_amdgcn_mfma_f32_16x16x32_bf16(a0, b1, acc[0][1], 0, 0, 0);
      acc[0][2] = __builtin_amdgcn_mfma_f32_16x16x32_bf16(a0, b2, acc[0][2], 0, 0, 0);
      acc[0][3] = __builtin_amdgcn_mfma_f32_16x16x32_bf16(a0, b3, acc[0][3], 0, 0, 0);
      acc[1][0] = __builtin_amdgcn_mfma_f32_16x16x32_bf16(a1, b0, acc[1][0], 0, 0, 0);
      acc[1][1] = __builtin_amdgcn_mfma_f32_16x16x32_bf16(a1, b1, acc[1][1], 0, 0, 0);
      acc[1][2] = __builtin_amdgcn_mfma_f32_16x16x32_bf16(a1, b2, acc[1][2], 0, 0, 0);
      acc[1][3] = __builtin_amdgcn_mfma_f32_16x16x32_bf16(a1, b3, acc[1][3], 0, 0, 0);
    }
    __syncthreads();   // drains vmcnt (next tile staged) + lgkm
    cur ^= 1;
  }

  // Epilogue: C/D row=(lane>>4)*4+reg -> co; col=lane&15 -> pos (verified layout)
#pragma unroll
  for (int i = 0; i < 2; i++) {
#pragma unroll
    for (int r = 0; r < 4; r++) {
      const int co = co_t + wco + i * 16 + kg * 4 + r;
      float* orow = out + ((size_t)n * CO + co) * 1024;
#pragma unroll
      for (int jf = 0; jf < 4; jf++) {
        const int pos = m0 + wpos + jf * 16 + ll;
        atomicAdd(orow + (pos & 1023), acc[i][jf][r]);
      }
    }
  }
}

extern "C" void kernel_launch(void* const* d_in, const int* in_sizes, int n_in,
                              void* d_out, int out_size, void* d_ws, size_t ws_size,
                              hipStream_t stream) {
  const float* x = (const float*)d_in[0];     // [8,512,64,64]
  const float* w = (const float*)d_in[1];     // [512,512,3,3]
  const float* bias = (const float*)d_in[2];  // [512]
  float* out = (float*)d_out;                 // [8,512,32,32]

  unsigned short* yt = (unsigned short*)d_ws;                    // 8*65*65*512 bf16
  unsigned short* wtb = yt + (size_t)NB * HY * HY * CI;          // 9*512*512 bf16

  fir_kernel<<<NB * (CI / CT) * 5, 256, 0, stream>>>(x, yt);     // 640 blocks
  wt_kernel<<<(CO * CI) / 256, 256, 0, stream>>>(w, wtb);        // 1024 blocks
  init_kernel<<<4096, 256, 0, stream>>>(bias, out);              // out = bias
  conv_kernel<<<1024, 256, 0, stream>>>(wtb, yt, out);           // splitK=2, 3 blk/CU
}

// Round 9
// 96.634 us; speedup vs baseline: 1.3459x; 1.2365x over previous
//
#include <hip/hip_runtime.h>
#include <stdint.h>

#define CI 512
#define CO 512
#define HI 64
#define WI 64
#define HY 65
#define NB 8

typedef __bf16 bf16x8 __attribute__((ext_vector_type(8)));
typedef float f32x4 __attribute__((ext_vector_type(4)));

__device__ __forceinline__ unsigned short f2bf(float f) {
  unsigned int u = __float_as_uint(f);
  return (unsigned short)((u + 0x7fffu + ((u >> 16) & 1u)) >> 16);
}

// async global->LDS, 16B per lane. LDS dest = wave-uniform base + lane*16.
__device__ __forceinline__ void async16(void* lds, const void* g) {
  __builtin_amdgcn_global_load_lds(
      (const __attribute__((address_space(1))) uint32_t*)g,
      (__attribute__((address_space(3))) uint32_t*)lds, 16, 0, 0);
}

// ---------------- Kernel A: FIR prefilter (LDS-tiled separable, prefetched) ----
// x: [8][512][64][64] f32 -> yt: [8][65][65][512] bf16 (channel-last)
// Round-9: register-prefetch next row's global loads so the HBM/L2 latency
// is off the per-stage critical path (was: latency-serial, VALUBusy 2.7%).
#define CT 32
#define RT 13

__global__ __launch_bounds__(256) void fir_kernel(const float* __restrict__ x,
                                                  unsigned short* __restrict__ yt) {
  __shared__ float raw[CT][WI + 1];
  __shared__ float hrow[4][HY][CT];

  const int tid = threadIdx.x;
  const int bid = blockIdx.x;
  const int n = bid / 80;
  const int rem = bid % 80;
  const int c0 = (rem / 5) * CT;
  const int r0 = (rem % 5) * RT;

  const float* xb = x + ((size_t)n * CI + c0) * (HI * WI);

  const int lc = tid >> 3;
  const int lq = tid & 7;
  const int c = tid & (CT - 1);
  const int sb = tid >> 5;

  float4 pA, pB;   // prefetched row (registers, in flight across a stage)
  auto preload = [&](int hr) {
    if ((unsigned)hr < (unsigned)HI) {
      const float* rowp = xb + ((size_t)lc * HI + hr) * WI;
      pA = *(const float4*)&rowp[lq * 4];
      pB = *(const float4*)&rowp[(lq + 8) * 4];
    }
  };

  // stage: write prefetched row hr into raw, issue preload(hr+1), compute h(hr)
  auto stage = [&](int hr) {
    __syncthreads();                       // raw free to overwrite
    if ((unsigned)hr < (unsigned)HI) {
      raw[lc][lq * 4 + 0] = pA.x; raw[lc][lq * 4 + 1] = pA.y;
      raw[lc][lq * 4 + 2] = pA.z; raw[lc][lq * 4 + 3] = pA.w;
      raw[lc][(lq + 8) * 4 + 0] = pB.x; raw[lc][(lq + 8) * 4 + 1] = pB.y;
      raw[lc][(lq + 8) * 4 + 2] = pB.z; raw[lc][(lq + 8) * 4 + 3] = pB.w;
    }
    preload(hr + 1);                       // next row: lands during compute
    __syncthreads();                       // raw visible
    const int slot = hr & 3;
    if ((unsigned)hr < (unsigned)HI) {
#pragma unroll
      for (int k = 0; k < 9; k++) {
        const int s = sb + (k << 3);
        if (s < HY) {
          float v = 0.f;
          if (s >= 2) v += raw[c][s - 2];
          if (s >= 1) v += 3.f * raw[c][s - 1];
          if (s <= 63) v += 3.f * raw[c][s];
          if (s <= 62) v += raw[c][s + 1];
          hrow[slot][s][c] = v;
        }
      }
    } else {
#pragma unroll
      for (int k = 0; k < 9; k++) {
        const int s = sb + (k << 3);
        if (s < HY) hrow[slot][s][c] = 0.f;
      }
    }
  };

  preload(r0 - 2);
  stage(r0 - 2);
  stage(r0 - 1);
  stage(r0);

  for (int i = 0; i < RT; i++) {
    const int r = r0 + i;
    stage(r + 1);
    __syncthreads();
    const int q0 = (r - 2) & 3, q1 = (r - 1) & 3, q2 = r & 3, q3 = (r + 1) & 3;
    unsigned short* yo = yt + (((size_t)n * HY + r) * HY) * CI + c0 + c;
#pragma unroll
    for (int k = 0; k < 9; k++) {
      const int s = sb + (k << 3);
      if (s < HY) {
        const float y = (hrow[q0][s][c] + 3.f * hrow[q1][s][c] +
                         3.f * hrow[q2][s][c] + hrow[q3][s][c]) * (1.f / 64.f);
        yo[(size_t)s * CI] = f2bf(y);
      }
    }
  }
}

// ---------------- Kernel B: weight transform ----------------
__global__ __launch_bounds__(256) void wt_kernel(const float* __restrict__ w,
                                                 unsigned short* __restrict__ wtb) {
  const int gid = blockIdx.x * 256 + threadIdx.x;
  const int ci = gid & (CI - 1);
  const int co = gid >> 9;
  const float* src = w + ((size_t)co * CI + ci) * 9;
#pragma unroll
  for (int t = 0; t < 9; t++) {
    wtb[((size_t)t * CO + co) * CI + ci] = f2bf(src[t]);
  }
}

// ---------------- Kernel C: implicit-GEMM conv (round-3 proven: 65.6us) -------
// Tile: 64 co x 128 pos, BK=64 ci, 72 k-steps (9 taps x 8 ci-blocks).
// Double-buffered LDS, global_load_lds staging issued before compute,
// XOR slot swizzle (slot ^= row&7) on both source and ds_read.
__global__ __launch_bounds__(256, 2) void conv_kernel(
    const unsigned short* __restrict__ wtb,
    const unsigned short* __restrict__ yt,
    const float* __restrict__ bias,
    float* __restrict__ out) {
  __shared__ unsigned short Alds[2][64 * 64];    // 16 KB
  __shared__ unsigned short Blds[2][128 * 64];   // 32 KB

  const int tid = threadIdx.x;
  // XCD swizzle: 8 co-tiles sharing a pos-tile octet land on one XCD chunk
  const int wgid = ((blockIdx.x & 7) << 6) | (blockIdx.x >> 3);
  const int co_t = (wgid & 7) << 6;
  const int m0 = (wgid >> 3) << 7;
  const int n = m0 >> 10;
  const int w = tid >> 6, l = tid & 63;

  // ---- staging lane-invariant global offsets (swizzled source) ----
  size_t aoff[2];
#pragma unroll
  for (int i = 0; i < 2; i++) {
    const int cch = i * 256 + w * 64 + l;        // A chunk id 0..511
    const int row = cch >> 3, s = cch & 7;
    aoff[i] = (size_t)(co_t + row) * CI + ((s ^ (row & 7)) << 3);
  }
  size_t boff[4];
#pragma unroll
  for (int i = 0; i < 4; i++) {
    const int cch = i * 256 + w * 64 + l;        // B chunk id 0..1023
    const int p = cch >> 3, s = cch & 7;
    const int pos = m0 + p;
    const int ho = (pos & 1023) >> 5, wo = pos & 31;
    boff[i] = (((size_t)n * HY + 2 * ho) * HY + 2 * wo) * CI + ((s ^ (p & 7)) << 3);
  }

  auto stage = [&](int b, int ks) {
    const int tap = ks >> 3;
    const int ci0 = (ks & 7) << 6;
    const int kh = tap / 3, kw = tap - kh * 3;
    const size_t ka = (size_t)tap * (CO * CI) + ci0;
    const size_t kb = (size_t)(kh * HY + kw) * CI + ci0;
    unsigned short* Ab = &Alds[b][0];
    unsigned short* Bb = &Blds[b][0];
#pragma unroll
    for (int i = 0; i < 2; i++)
      async16(Ab + (size_t)(i * 256 + w * 64 + l) * 8, wtb + ka + aoff[i]);
#pragma unroll
    for (int i = 0; i < 4; i++)
      async16(Bb + (size_t)(i * 256 + w * 64 + l) * 8, yt + kb + boff[i]);
  };

  // ---- compute-side fragment addresses (swizzled read) ----
  const int wco = (w >> 1) << 5;   // 0 / 32
  const int wpos = (w & 1) << 6;   // 0 / 64
  const int ll = l & 15, kg = l >> 4;
  const int a7 = ll & 7;

  int aidx[2][2], bidx[4][2];
#pragma unroll
  for (int m = 0; m < 2; m++)
#pragma unroll
    for (int kk = 0; kk < 2; kk++)
      aidx[m][kk] = (wco + m * 16 + ll) * 64 + ((((kk << 2) | kg) ^ a7) << 3);
#pragma unroll
  for (int nf = 0; nf < 4; nf++)
#pragma unroll
    for (int kk = 0; kk < 2; kk++)
      bidx[nf][kk] = (wpos + nf * 16 + ll) * 64 + ((((kk << 2) | kg) ^ a7) << 3);

  f32x4 acc[2][4] = {};

  stage(0, 0);
  __syncthreads();

  int cur = 0;
  for (int ks = 0; ks < 72; ks++) {
    if (ks < 71) stage(cur ^ 1, ks + 1);   // loads in flight across compute
    const unsigned short* Ac = &Alds[cur][0];
    const unsigned short* Bc = &Blds[cur][0];
#pragma unroll
    for (int kk = 0; kk < 2; kk++) {
      const bf16x8 a0 = *(const bf16x8*)(Ac + aidx[0][kk]);
      const bf16x8 a1 = *(const bf16x8*)(Ac + aidx[1][kk]);
      const bf16x8 b0 = *(const bf16x8*)(Bc + bidx[0][kk]);
      const bf16x8 b1 = *(const bf16x8*)(Bc + bidx[1][kk]);
      const bf16x8 b2 = *(const bf16x8*)(Bc + bidx[2][kk]);
      const bf16x8 b3 = *(const bf16x8*)(Bc + bidx[3][kk]);
      acc[0][0] = __builtin_amdgcn_mfma_f32_16x16x32_bf16(a0, b0, acc[0][0], 0, 0, 0);
      acc[0][1] = __builtin_amdgcn_mfma_f32_16x16x32_bf16(a0, b1, acc[0][1], 0, 0, 0);
      acc[0][2] = __builtin_amdgcn_mfma_f32_16x16x32_bf16(a0, b2, acc[0][2], 0, 0, 0);
      acc[0][3] = __builtin_amdgcn_mfma_f32_16x16x32_bf16(a0, b3, acc[0][3], 0, 0, 0);
      acc[1][0] = __builtin_amdgcn_mfma_f32_16x16x32_bf16(a1, b0, acc[1][0], 0, 0, 0);
      acc[1][1] = __builtin_amdgcn_mfma_f32_16x16x32_bf16(a1, b1, acc[1][1], 0, 0, 0);
      acc[1][2] = __builtin_amdgcn_mfma_f32_16x16x32_bf16(a1, b2, acc[1][2], 0, 0, 0);
      acc[1][3] = __builtin_amdgcn_mfma_f32_16x16x32_bf16(a1, b3, acc[1][3], 0, 0, 0);
    }
    __syncthreads();   // drains vmcnt (next tile staged) + lgkm
    cur ^= 1;
  }

  // Epilogue: C/D row=(lane>>4)*4+reg -> co; col=lane&15 -> pos (verified layout)
#pragma unroll
  for (int i = 0; i < 2; i++) {
#pragma unroll
    for (int r = 0; r < 4; r++) {
      const int co = co_t + wco + i * 16 + kg * 4 + r;
      const float bv = bias[co];
#pragma unroll
      for (int j = 0; j < 4; j++) {
        const int pos = m0 + wpos + j * 16 + ll;
        const int ho = (pos & 1023) >> 5;
        const int wo = pos & 31;
        out[(((size_t)n * CO + co) * 32 + ho) * 32 + wo] = acc[i][j][r] + bv;
      }
    }
  }
}

extern "C" void kernel_launch(void* const* d_in, const int* in_sizes, int n_in,
                              void* d_out, int out_size, void* d_ws, size_t ws_size,
                              hipStream_t stream) {
  const float* x = (const float*)d_in[0];     // [8,512,64,64]
  const float* w = (const float*)d_in[1];     // [512,512,3,3]
  const float* bias = (const float*)d_in[2];  // [512]
  float* out = (float*)d_out;                 // [8,512,32,32]

  unsigned short* yt = (unsigned short*)d_ws;                    // 8*65*65*512 bf16
  unsigned short* wtb = yt + (size_t)NB * HY * HY * CI;          // 9*512*512 bf16

  fir_kernel<<<NB * (CI / CT) * 5, 256, 0, stream>>>(x, yt);     // 640 blocks
  wt_kernel<<<(CO * CI) / 256, 256, 0, stream>>>(w, wtb);        // 1024 blocks
  conv_kernel<<<512, 256, 0, stream>>>(wtb, yt, bias, out);      // 512 blocks
}